// Round 10
// baseline (1206.573 us; speedup 1.0000x reference)
//
#include <hip/hip_runtime.h>

// ---------- types ----------
typedef __bf16 bf16x8 __attribute__((ext_vector_type(8)));
typedef float  f32x4  __attribute__((ext_vector_type(4)));
typedef unsigned short u16x8 __attribute__((ext_vector_type(8)));
typedef unsigned short u16x4 __attribute__((ext_vector_type(4)));

__device__ __forceinline__ unsigned short f2bf(float f) {
  union { float f; unsigned u; } v; v.f = f;
  unsigned r = v.u + 0x7fffu + ((v.u >> 16) & 1u);  // RNE
  return (unsigned short)(r >> 16);
}

__device__ __forceinline__ float bf2f(unsigned short b) {
  union { unsigned u; float f; } v; v.u = (unsigned)b << 16;
  return v.f;
}

__device__ __forceinline__ void gload16(const unsigned short* g, unsigned short* l) {
  __builtin_amdgcn_global_load_lds(
      (const __attribute__((address_space(1))) unsigned int*)g,
      (__attribute__((address_space(3))) unsigned int*)l,
      16, 0, 0);
}

__device__ __forceinline__ void nt_store4(float* p, f32x4 v) {
  __builtin_nontemporal_store(v, (f32x4*)p);
}

#define WOFF 50331648   // weights_cat elems = 4*1024*12288

// swizzled E index: [32][1024] u16, 16B slots XORed with row&7
__device__ __forceinline__ int eidx(int row, int col) {
  return row * 1024 + ((((col >> 3) ^ (row & 7)) << 3) | (col & 7));
}

// ---------- kernel 1: fused prep ----------
__global__ __launch_bounds__(256) void prep(
    const float* __restrict__ x, const float* __restrict__ Wq, const float* __restrict__ Wk,
    const float* __restrict__ Wv, const float* __restrict__ Wd,
    unsigned short* __restrict__ xb, unsigned short* __restrict__ wb, unsigned short* __restrict__ wdb)
{
  __shared__ float t[32][33];
  const int bid = blockIdx.x, tid = threadIdx.x;
  if (bid < 1536) {
    int i = (bid * 256 + tid) * 8;
    f32x4 v0 = *(const f32x4*)&x[i];
    f32x4 v1 = *(const f32x4*)&x[i + 4];
    u16x8 o;
    for (int j = 0; j < 4; j++) { o[j] = f2bf(v0[j]); o[j + 4] = f2bf(v1[j]); }
    *(u16x8*)&xb[i] = o;
    return;
  }
  const int tx = tid & 31, ty = tid >> 5;
  if (bid < 3264) {
    int q = bid - 1536;
    int bx = q & 1; q >>= 1;
    int by = q % 24, zz = q / 24;
    int m = zz / 12;
    const float* in = (m == 0 ? Wq : m == 1 ? Wk : Wv) + (long)(zz % 12) * 49152;
    unsigned short* ob = wb + (long)zz * 49152;
    int c = bx * 32 + tx, r0 = by * 32;
    for (int i = ty; i < 32; i += 8) t[i][tx] = in[(long)(r0 + i) * 64 + c];
    __syncthreads();
    int c0 = bx * 32;
    for (int i = ty; i < 32; i += 8) ob[(long)(c0 + i) * 768 + r0 + tx] = f2bf(t[tx][i]);
    return;
  }
  {
    int q = bid - 3264;
    int bx = q % 24, by = q / 24;
    int c = bx * 32 + tx, r0 = by * 32;
    for (int i = ty; i < 32; i += 8) t[i][tx] = Wd[(long)(r0 + i) * 768 + c];
    __syncthreads();
    int c0 = bx * 32;
    for (int i = ty; i < 32; i += 8) wdb[(long)(c0 + i) * 768 + r0 + tx] = f2bf(t[tx][i]);
  }
}

// ---------- kernel 2: QKV GEMM ----------
__global__ __launch_bounds__(256) void qkv_gemm(
    const unsigned short* __restrict__ xb, const unsigned short* __restrict__ wb,
    const float* __restrict__ bq, const float* __restrict__ bk, const float* __restrict__ bv,
    unsigned short* __restrict__ Qb, unsigned short* __restrict__ Kb, unsigned short* __restrict__ Vt)
{
  __shared__ unsigned short As[2][4096];
  __shared__ unsigned short Bs[2][4096];
  const int tid = threadIdx.x;
  const int bid = blockIdx.x;
  const int swz = (bid & 7) * 72 + (bid >> 3);
  const int bn = (swz % 18) * 128, bm = (swz / 18) * 128;
  const int w = tid >> 6, l = tid & 63;
  const int wr = w >> 1, wc = w & 1;
  const int lr = l & 15, lg = l >> 4;
  const int lofs = w << 9;

  f32x4 acc[4][4];
  for (int i = 0; i < 4; i++) for (int j = 0; j < 4; j++) acc[i][j] = {0.f, 0.f, 0.f, 0.f};

  const unsigned short* ga = xb + (long)(bm + (tid >> 2)) * 768 + (tid & 3) * 8;
  const unsigned short* gb = wb + (long)(bn + (tid >> 2)) * 768 + (tid & 3) * 8;

  gload16(ga,            &As[0][lofs]);
  gload16(ga + 64 * 768, &As[0][lofs + 2048]);
  gload16(gb,            &Bs[0][lofs]);
  gload16(gb + 64 * 768, &Bs[0][lofs + 2048]);
  __syncthreads();

  int cur = 0;
  for (int t = 0; t < 24; t++) {
    if (t < 23) {
      int k0 = (t + 1) * 32;
      gload16(ga + k0,            &As[cur ^ 1][lofs]);
      gload16(ga + k0 + 64 * 768, &As[cur ^ 1][lofs + 2048]);
      gload16(gb + k0,            &Bs[cur ^ 1][lofs]);
      gload16(gb + k0 + 64 * 768, &Bs[cur ^ 1][lofs + 2048]);
    }
    bf16x8 af[4], bfv[4];
    for (int i = 0; i < 4; i++) af[i]  = *(const bf16x8*)&As[cur][(wr * 64 + i * 16 + lr) * 32 + lg * 8];
    for (int j = 0; j < 4; j++) bfv[j] = *(const bf16x8*)&Bs[cur][(wc * 64 + j * 16 + lr) * 32 + lg * 8];
    for (int i = 0; i < 4; i++)
      for (int j = 0; j < 4; j++)
        acc[i][j] = __builtin_amdgcn_mfma_f32_16x16x32_bf16(af[i], bfv[j], acc[i][j], 0, 0, 0);
    __syncthreads();
    cur ^= 1;
  }

  for (int i = 0; i < 4; i++) for (int j = 0; j < 4; j++) {
    int col = bn + wc * 64 + j * 16 + lr;
    int m = col / 768, rc = col % 768;
    int h = rc >> 6, d = rc & 63;
    const float* bias = (m == 0) ? bq : (m == 1) ? bk : bv;
    float bb = bias[rc];
    for (int r = 0; r < 4; r++) {
      int row = bm + wr * 64 + i * 16 + lg * 4 + r;
      int b = row >> 10, s = row & 1023;
      float v = acc[i][j][r] + bb;
      if (m == 0)      Qb[((b * 12 + h) << 16) + (s << 6) + d] = f2bf(v * 0.125f);
      else if (m == 1) Kb[((b * 12 + h) << 16) + (s << 6) + d] = f2bf(v);
      else             Vt[((b * 12 + h) << 16) + (d << 10) + s] = f2bf(v);
    }
  }
}

// ---------- kernel 3: attention — ABLATION TEMPLATE (v4 body) ----------
// V=3: Q+QK^T+exp+reduce only (sink). V=2: +weights store. V=1: +PV+ctx (no weights).
// V=0: full. All variants write only correct values; V0 runs last.
template<int V>
__global__ __launch_bounds__(512) void attn_kernel(
    const unsigned short* __restrict__ Qb, const unsigned short* __restrict__ Kb,
    const unsigned short* __restrict__ Vt,
    float* __restrict__ wout, unsigned short* __restrict__ ctx, int reps)
{
  extern __shared__ char smem[];
  unsigned short* E  = (unsigned short*)smem;             // 65536 B: [32][1024] swz
  unsigned short* Qs = (unsigned short*)(smem + 65536);   // 4608 B
  float* sred = (float*)(smem + 70144);                   // 1024 B
  float* sfin = (float*)(smem + 71168);                   // 128 B

  const int bid = blockIdx.x;
  const int swz = (bid & 7) * 192 + (bid >> 3);
  const int bh = swz >> 5;
  const int q0 = (swz & 31) * 32;
  const int b = bh / 12, h = bh % 12;
  const int tid = threadIdx.x;
  const int w = tid >> 6, l = tid & 63, lr = l & 15, lg = l >> 4;

#pragma unroll 1
  for (int _r = 0; _r < reps; ++_r) {
    int z = 0; asm volatile("" : "+v"(z));
    const unsigned short* Qg = Qb + z + (bh << 16);
    const unsigned short* Kg = Kb + z + (bh << 16);
    const unsigned short* Vg = Vt + z + (bh << 16);

    if (tid < 256) {
      int row = tid >> 3, c = (tid & 7) * 8;
      *(u16x8*)&Qs[row * 72 + c] = *(const u16x8*)&Qg[(q0 + row) * 64 + c];
    }
    __syncthreads();

    // QK^T
    bf16x8 qa[2][2];
    for (int ri = 0; ri < 2; ri++) {
      qa[ri][0] = *(const bf16x8*)&Qs[(ri * 16 + lr) * 72 + lg * 8];
      qa[ri][1] = *(const bf16x8*)&Qs[(ri * 16 + lr) * 72 + 32 + lg * 8];
    }
    f32x4 sc[2][8];
#pragma unroll
    for (int cf = 0; cf < 8; cf++) {
      int colb = w * 128 + cf * 16;
      bf16x8 kb0 = *(const bf16x8*)&Kg[(colb + lr) * 64 + lg * 8];
      bf16x8 kb1 = *(const bf16x8*)&Kg[(colb + lr) * 64 + 32 + lg * 8];
#pragma unroll
      for (int ri = 0; ri < 2; ri++) {
        f32x4 a = {0.f, 0.f, 0.f, 0.f};
        a = __builtin_amdgcn_mfma_f32_16x16x32_bf16(qa[ri][0], kb0, a, 0, 0, 0);
        a = __builtin_amdgcn_mfma_f32_16x16x32_bf16(qa[ri][1], kb1, a, 0, 0, 0);
        sc[ri][cf] = a;
      }
    }

    // exp -> swizzled E + per-wave row sums
    float sm[2][4] = {{0.f, 0.f, 0.f, 0.f}, {0.f, 0.f, 0.f, 0.f}};
#pragma unroll
    for (int cf = 0; cf < 8; cf++)
#pragma unroll
      for (int ri = 0; ri < 2; ri++)
#pragma unroll
        for (int r = 0; r < 4; r++) {
          float e = __expf(sc[ri][cf][r]);
          sm[ri][r] += e;
          E[eidx(ri * 16 + lg * 4 + r, w * 128 + cf * 16 + lr)] = f2bf(e);
        }
#pragma unroll
    for (int ri = 0; ri < 2; ri++)
#pragma unroll
      for (int r = 0; r < 4; r++) {
        float s = sm[ri][r];
        for (int o = 8; o >= 1; o >>= 1) s += __shfl_xor(s, o, 16);
        if (lr == 0) sred[w * 32 + ri * 16 + lg * 4 + r] = s;
      }
    __syncthreads();   // E + sred visible

    if (tid < 32) {
      float s = 0.f;
      for (int ww = 0; ww < 8; ww++) s += sred[ww * 32 + tid];
      sfin[tid] = 1.f / s;
    }

    // PV (V=0,1)
    int ri = w >> 2, cf = w & 3;
    f32x4 acc = {0.f, 0.f, 0.f, 0.f};
    if (V <= 1) {
#pragma unroll
      for (int ks = 0; ks < 32; ks++) {
        int kk = ks * 32;
        bf16x8 pa = *(const bf16x8*)&E[eidx(ri * 16 + lr, kk + lg * 8)];
        bf16x8 vb = *(const bf16x8*)&Vg[(cf * 16 + lr) * 1024 + kk + lg * 8];
        acc = __builtin_amdgcn_mfma_f32_16x16x32_bf16(pa, vb, acc, 0, 0, 0);
      }
    }
    __syncthreads();   // sfin visible

    if (V <= 1) {
      // ctx store
#pragma unroll
      for (int r = 0; r < 4; r++) {
        int row = ri * 16 + lg * 4 + r;
        float v = acc[r] * sfin[row];
        ctx[(long)(b * 1024 + q0 + row) * 768 + h * 64 + cf * 16 + lr] = f2bf(v);
      }
    }

    if (V == 0 || V == 2) {
      // weights store tail
      float* wbase = wout + (long)(b * 1024 + q0) * 12288 + h * 1024;
#pragma unroll
      for (int it = 0; it < 16; it++) {
        int vidx = it * 512 + tid;
        int row = vidx >> 8, c4 = (vidx & 255) * 4;
        float rs = sfin[row];
        u16x4 ev = *(const u16x4*)&E[eidx(row, c4)];
        f32x4 o;
        for (int t = 0; t < 4; t++) o[t] = bf2f(ev[t]) * rs;
        *(f32x4*)&wbase[(long)row * 12288 + c4] = o;
      }
    }

    if (V == 3) {
      // keep the whole chain live without stores (rule 17)
      unsigned short ev = E[eidx(tid & 31, (tid * 33) & 1023)];
      float sv = sfin[tid & 31];
      asm volatile("" :: "v"((int)ev), "v"(sv));
    }
    __syncthreads();   // rep boundary
  }
}

// ---------- kernel 4: dense GEMM ----------
__global__ __launch_bounds__(256) void dense_gemm(
    const unsigned short* __restrict__ ctx, const unsigned short* __restrict__ wdb,
    const float* __restrict__ bd, float* __restrict__ y)
{
  __shared__ unsigned short As[2][2048];
  __shared__ unsigned short Bs[2][4096];
  const int tid = threadIdx.x;
  const int bid = blockIdx.x;
  const int swz = (bid & 7) * 48 + (bid >> 3);
  const int bn = (swz % 6) * 128, bm = (swz / 6) * 64;
  const int w = tid >> 6, l = tid & 63;
  const int wr = w >> 1, wc = w & 1;
  const int lr = l & 15, lg = l >> 4;
  const int lofs = w << 9;

  f32x4 acc[2][4];
  for (int i = 0; i < 2; i++) for (int j = 0; j < 4; j++) acc[i][j] = {0.f, 0.f, 0.f, 0.f};

  const unsigned short* ga = ctx + (long)(bm + (tid >> 2)) * 768 + (tid & 3) * 8;
  const unsigned short* gb = wdb + (long)(bn + (tid >> 2)) * 768 + (tid & 3) * 8;

  gload16(ga,            &As[0][lofs]);
  gload16(gb,            &Bs[0][lofs]);
  gload16(gb + 64 * 768, &Bs[0][lofs + 2048]);
  __syncthreads();

  int cur = 0;
  for (int t = 0; t < 24; t++) {
    if (t < 23) {
      int k0 = (t + 1) * 32;
      gload16(ga + k0,            &As[cur ^ 1][lofs]);
      gload16(gb + k0,            &Bs[cur ^ 1][lofs]);
      gload16(gb + k0 + 64 * 768, &Bs[cur ^ 1][lofs + 2048]);
    }
    bf16x8 af[2], bfv[4];
    for (int i = 0; i < 2; i++) af[i]  = *(const bf16x8*)&As[cur][(wr * 32 + i * 16 + lr) * 32 + lg * 8];
    for (int j = 0; j < 4; j++) bfv[j] = *(const bf16x8*)&Bs[cur][(wc * 64 + j * 16 + lr) * 32 + lg * 8];
    for (int i = 0; i < 2; i++)
      for (int j = 0; j < 4; j++)
        acc[i][j] = __builtin_amdgcn_mfma_f32_16x16x32_bf16(af[i], bfv[j], acc[i][j], 0, 0, 0);
    __syncthreads();
    cur ^= 1;
  }

  for (int i = 0; i < 2; i++) for (int j = 0; j < 4; j++) {
    int col = bn + wc * 64 + j * 16 + lr;
    float bb = bd[col];
    for (int r = 0; r < 4; r++) {
      int row = bm + wr * 32 + i * 16 + lg * 4 + r;
      y[(long)row * 768 + col] = acc[i][j][r] + bb;
    }
  }
}

// ---------- kernel 5: LayerNorm ----------
__global__ __launch_bounds__(256) void ln_kernel(
    const float* __restrict__ y,
    const float* __restrict__ gamma, const float* __restrict__ beta,
    float* __restrict__ out)
{
  int w = threadIdx.x >> 6, l = threadIdx.x & 63;
  long row = blockIdx.x * 4 + w;
  const float* yr = y + row * 768;
  f32x4 v[3];
  float s = 0.f, ss = 0.f;
  for (int j = 0; j < 3; j++) {
    int c = j * 256 + l * 4;
    f32x4 t = *(const f32x4*)&yr[c];
    for (int q = 0; q < 4; q++) { s += t[q]; ss += t[q] * t[q]; }
    v[j] = t;
  }
  for (int o = 32; o >= 1; o >>= 1) { s += __shfl_xor(s, o); ss += __shfl_xor(ss, o); }
  float mu = s * (1.f / 768.f);
  float var = ss * (1.f / 768.f) - mu * mu;
  float rs = rsqrtf(var + 1e-12f);
  float* orow = out + row * 768;
  for (int j = 0; j < 3; j++) {
    int c = j * 256 + l * 4;
    f32x4 g = *(const f32x4*)&gamma[c];
    f32x4 be = *(const f32x4*)&beta[c];
    f32x4 o;
    for (int q = 0; q < 4; q++) o[q] = (v[j][q] - mu) * rs * g[q] + be[q];
    nt_store4(&orow[c], o);
  }
}

// ---------- launch ----------
extern "C" void kernel_launch(void* const* d_in, const int* in_sizes, int n_in,
                              void* d_out, int out_size, void* d_ws, size_t ws_size,
                              hipStream_t stream) {
  const float* x     = (const float*)d_in[0];
  const float* Wq    = (const float*)d_in[1];
  const float* bq    = (const float*)d_in[2];
  const float* Wk    = (const float*)d_in[3];
  const float* bk    = (const float*)d_in[4];
  const float* Wv    = (const float*)d_in[5];
  const float* bv    = (const float*)d_in[6];
  const float* Wd    = (const float*)d_in[7];
  const float* bd    = (const float*)d_in[8];
  const float* gamma = (const float*)d_in[9];
  const float* beta  = (const float*)d_in[10];
  float* out = (float*)d_out;

  char* ws = (char*)d_ws;
  unsigned short* xb  = (unsigned short*)(ws);
  unsigned short* wb  = (unsigned short*)(ws + 6291456);
  unsigned short* wdb = (unsigned short*)(ws + 9830400);
  unsigned short* Qb  = (unsigned short*)(ws + 11010048);
  unsigned short* Kb  = (unsigned short*)(ws + 17301504);
  unsigned short* Vt  = (unsigned short*)(ws + 23592960);
  unsigned short* ctx = (unsigned short*)(ws + 29884416);
  float*          yws = (float*)(ws + 11010048);

  prep<<<3840, 256, 0, stream>>>(x, Wq, Wk, Wv, Wd, xb, wb, wdb);
  qkv_gemm<<<576, 256, 0, stream>>>(xb, wb, bq, bk, bv, Qb, Kb, Vt);
  // ablation ladder: V3 (core) -> V2 (+weights) -> V1 (+PV/ctx) -> V0 (full, last)
  attn_kernel<3><<<1536, 512, 71296, stream>>>(Qb, Kb, Vt, out, ctx, 10);
  attn_kernel<2><<<1536, 512, 71296, stream>>>(Qb, Kb, Vt, out, ctx, 4);
  attn_kernel<1><<<1536, 512, 71296, stream>>>(Qb, Kb, Vt, out, ctx, 4);
  attn_kernel<0><<<1536, 512, 71296, stream>>>(Qb, Kb, Vt, out, ctx, 2);
  dense_gemm<<<384, 256, 0, stream>>>(ctx, wdb, bd, yws);
  ln_kernel<<<1024, 256, 0, stream>>>(yws, gamma, beta, out + WOFF);
}

// Round 11
// 155.328 us; speedup vs baseline: 7.7679x; 7.7679x over previous
//
#include <hip/hip_runtime.h>

// ---------- types ----------
typedef __bf16 bf16x8 __attribute__((ext_vector_type(8)));
typedef float  f32x4  __attribute__((ext_vector_type(4)));
typedef unsigned short u16x8 __attribute__((ext_vector_type(8)));
typedef unsigned short u16x4 __attribute__((ext_vector_type(4)));

__device__ __forceinline__ unsigned short f2bf(float f) {
  union { float f; unsigned u; } v; v.f = f;
  unsigned r = v.u + 0x7fffu + ((v.u >> 16) & 1u);  // RNE
  return (unsigned short)(r >> 16);
}

__device__ __forceinline__ float bf2f(unsigned short b) {
  union { unsigned u; float f; } v; v.u = (unsigned)b << 16;
  return v.f;
}

__device__ __forceinline__ void gload16(const unsigned short* g, unsigned short* l) {
  __builtin_amdgcn_global_load_lds(
      (const __attribute__((address_space(1))) unsigned int*)g,
      (__attribute__((address_space(3))) unsigned int*)l,
      16, 0, 0);
}

__device__ __forceinline__ void nt_store4(float* p, f32x4 v) {
  __builtin_nontemporal_store(v, (f32x4*)p);
}

#define WOFF 50331648   // weights_cat elems = 4*1024*12288

// swizzled E index: [32][1024] u16, 16B slots XORed with row&7
__device__ __forceinline__ int eidx(int row, int col) {
  return row * 1024 + ((((col >> 3) ^ (row & 7)) << 3) | (col & 7));
}

// ---------- kernel 1: fused prep ----------
__global__ __launch_bounds__(256) void prep(
    const float* __restrict__ x, const float* __restrict__ Wq, const float* __restrict__ Wk,
    const float* __restrict__ Wv, const float* __restrict__ Wd,
    unsigned short* __restrict__ xb, unsigned short* __restrict__ wb, unsigned short* __restrict__ wdb)
{
  __shared__ float t[32][33];
  const int bid = blockIdx.x, tid = threadIdx.x;
  if (bid < 1536) {
    int i = (bid * 256 + tid) * 8;
    f32x4 v0 = *(const f32x4*)&x[i];
    f32x4 v1 = *(const f32x4*)&x[i + 4];
    u16x8 o;
    for (int j = 0; j < 4; j++) { o[j] = f2bf(v0[j]); o[j + 4] = f2bf(v1[j]); }
    *(u16x8*)&xb[i] = o;
    return;
  }
  const int tx = tid & 31, ty = tid >> 5;
  if (bid < 3264) {
    int q = bid - 1536;
    int bx = q & 1; q >>= 1;
    int by = q % 24, zz = q / 24;
    int m = zz / 12;
    const float* in = (m == 0 ? Wq : m == 1 ? Wk : Wv) + (long)(zz % 12) * 49152;
    unsigned short* ob = wb + (long)zz * 49152;
    int c = bx * 32 + tx, r0 = by * 32;
    for (int i = ty; i < 32; i += 8) t[i][tx] = in[(long)(r0 + i) * 64 + c];
    __syncthreads();
    int c0 = bx * 32;
    for (int i = ty; i < 32; i += 8) ob[(long)(c0 + i) * 768 + r0 + tx] = f2bf(t[tx][i]);
    return;
  }
  {
    int q = bid - 3264;
    int bx = q % 24, by = q / 24;
    int c = bx * 32 + tx, r0 = by * 32;
    for (int i = ty; i < 32; i += 8) t[i][tx] = Wd[(long)(r0 + i) * 768 + c];
    __syncthreads();
    int c0 = bx * 32;
    for (int i = ty; i < 32; i += 8) wdb[(long)(c0 + i) * 768 + r0 + tx] = f2bf(t[tx][i]);
  }
}

// ---------- kernel 2: QKV GEMM ----------
__global__ __launch_bounds__(256) void qkv_gemm(
    const unsigned short* __restrict__ xb, const unsigned short* __restrict__ wb,
    const float* __restrict__ bq, const float* __restrict__ bk, const float* __restrict__ bv,
    unsigned short* __restrict__ Qb, unsigned short* __restrict__ Kb, unsigned short* __restrict__ Vt)
{
  __shared__ unsigned short As[2][4096];
  __shared__ unsigned short Bs[2][4096];
  const int tid = threadIdx.x;
  const int bid = blockIdx.x;
  const int swz = (bid & 7) * 72 + (bid >> 3);
  const int bn = (swz % 18) * 128, bm = (swz / 18) * 128;
  const int w = tid >> 6, l = tid & 63;
  const int wr = w >> 1, wc = w & 1;
  const int lr = l & 15, lg = l >> 4;
  const int lofs = w << 9;

  f32x4 acc[4][4];
  for (int i = 0; i < 4; i++) for (int j = 0; j < 4; j++) acc[i][j] = {0.f, 0.f, 0.f, 0.f};

  const unsigned short* ga = xb + (long)(bm + (tid >> 2)) * 768 + (tid & 3) * 8;
  const unsigned short* gb = wb + (long)(bn + (tid >> 2)) * 768 + (tid & 3) * 8;

  gload16(ga,            &As[0][lofs]);
  gload16(ga + 64 * 768, &As[0][lofs + 2048]);
  gload16(gb,            &Bs[0][lofs]);
  gload16(gb + 64 * 768, &Bs[0][lofs + 2048]);
  __syncthreads();

  int cur = 0;
  for (int t = 0; t < 24; t++) {
    if (t < 23) {
      int k0 = (t + 1) * 32;
      gload16(ga + k0,            &As[cur ^ 1][lofs]);
      gload16(ga + k0 + 64 * 768, &As[cur ^ 1][lofs + 2048]);
      gload16(gb + k0,            &Bs[cur ^ 1][lofs]);
      gload16(gb + k0 + 64 * 768, &Bs[cur ^ 1][lofs + 2048]);
    }
    bf16x8 af[4], bfv[4];
    for (int i = 0; i < 4; i++) af[i]  = *(const bf16x8*)&As[cur][(wr * 64 + i * 16 + lr) * 32 + lg * 8];
    for (int j = 0; j < 4; j++) bfv[j] = *(const bf16x8*)&Bs[cur][(wc * 64 + j * 16 + lr) * 32 + lg * 8];
    for (int i = 0; i < 4; i++)
      for (int j = 0; j < 4; j++)
        acc[i][j] = __builtin_amdgcn_mfma_f32_16x16x32_bf16(af[i], bfv[j], acc[i][j], 0, 0, 0);
    __syncthreads();
    cur ^= 1;
  }

  for (int i = 0; i < 4; i++) for (int j = 0; j < 4; j++) {
    int col = bn + wc * 64 + j * 16 + lr;
    int m = col / 768, rc = col % 768;
    int h = rc >> 6, d = rc & 63;
    const float* bias = (m == 0) ? bq : (m == 1) ? bk : bv;
    float bb = bias[rc];
    for (int r = 0; r < 4; r++) {
      int row = bm + wr * 64 + i * 16 + lg * 4 + r;
      int b = row >> 10, s = row & 1023;
      float v = acc[i][j][r] + bb;
      if (m == 0)      Qb[((b * 12 + h) << 16) + (s << 6) + d] = f2bf(v * 0.125f);
      else if (m == 1) Kb[((b * 12 + h) << 16) + (s << 6) + d] = f2bf(v);
      else             Vt[((b * 12 + h) << 16) + (d << 10) + s] = f2bf(v);
    }
  }
}

// ---------- kernel 3: attention v6 — ONE barrier, wave-split phase 2 ----------
// 1536 blocks (48 bh x 32 q-blocks), 512 threads (8 waves), 2 blocks/CU.
// Phase 1 (all waves): direct Q loads, QK^T (wave owns 128 k-cols), exp -> swz E,
//   per-wave row sums -> sred.  ONE __syncthreads().
// Phase 2: waves 0-3 PV+ctx (setprio around MFMA), waves 4-7 stream weights store.
// Each wave self-computes 1/rowsum from sred in registers (shfl broadcast).
__global__ __launch_bounds__(512, 4) void attn_kernel(
    const unsigned short* __restrict__ Qb, const unsigned short* __restrict__ Kb,
    const unsigned short* __restrict__ Vt,
    float* __restrict__ wout, unsigned short* __restrict__ ctx)
{
  extern __shared__ char smem[];
  unsigned short* E = (unsigned short*)smem;          // 65536 B: [32][1024] swz
  float* sred = (float*)(smem + 65536);               // 1024 B: [8 waves][32 rows]

  const int bid = blockIdx.x;
  const int swz = (bid & 7) * 192 + (bid >> 3);   // 1536 = 8 * 192
  const int bh = swz >> 5;
  const int q0 = (swz & 31) * 32;
  const int b = bh / 12, h = bh % 12;
  const int tid = threadIdx.x;
  const int w = tid >> 6, l = tid & 63, lr = l & 15, lg = l >> 4;
  const unsigned short* Qg = Qb + (bh << 16);
  const unsigned short* Kg = Kb + (bh << 16);
  const unsigned short* Vg = Vt + (bh << 16);

  // ---- phase 1: QK^T with direct Q loads (no staging, no barrier) ----
  bf16x8 qa[2][2];
#pragma unroll
  for (int ri = 0; ri < 2; ri++)
#pragma unroll
    for (int ks = 0; ks < 2; ks++)
      qa[ri][ks] = *(const bf16x8*)&Qg[(q0 + ri * 16 + lr) * 64 + ks * 32 + lg * 8];

  f32x4 sc[2][8];
#pragma unroll
  for (int cf = 0; cf < 8; cf++) {
    int colb = w * 128 + cf * 16;
    bf16x8 kb0 = *(const bf16x8*)&Kg[(colb + lr) * 64 + lg * 8];
    bf16x8 kb1 = *(const bf16x8*)&Kg[(colb + lr) * 64 + 32 + lg * 8];
#pragma unroll
    for (int ri = 0; ri < 2; ri++) {
      f32x4 a = {0.f, 0.f, 0.f, 0.f};
      a = __builtin_amdgcn_mfma_f32_16x16x32_bf16(qa[ri][0], kb0, a, 0, 0, 0);
      a = __builtin_amdgcn_mfma_f32_16x16x32_bf16(qa[ri][1], kb1, a, 0, 0, 0);
      sc[ri][cf] = a;
    }
  }

  // exp (no max-sub: |score| <~ 8) -> swizzled E + per-wave row sums
  float sm[2][4] = {{0.f, 0.f, 0.f, 0.f}, {0.f, 0.f, 0.f, 0.f}};
#pragma unroll
  for (int cf = 0; cf < 8; cf++)
#pragma unroll
    for (int ri = 0; ri < 2; ri++)
#pragma unroll
      for (int r = 0; r < 4; r++) {
        float e = __expf(sc[ri][cf][r]);
        sm[ri][r] += e;
        E[eidx(ri * 16 + lg * 4 + r, w * 128 + cf * 16 + lr)] = f2bf(e);
      }
#pragma unroll
  for (int ri = 0; ri < 2; ri++)
#pragma unroll
    for (int r = 0; r < 4; r++) {
      float s = sm[ri][r];
      for (int o = 8; o >= 1; o >>= 1) s += __shfl_xor(s, o, 16);
      if (lr == 0) sred[w * 32 + ri * 16 + lg * 4 + r] = s;
    }

  __syncthreads();   // the ONLY barrier

  // per-wave reciprocal row-sums: lane L holds 1/sum of row (L&31)
  float s_acc = 0.f;
  {
    int row_l = l & 31;
#pragma unroll
    for (int ww = 0; ww < 8; ww++) s_acc += sred[ww * 32 + row_l];
  }
  const float sfin_r = 1.f / s_acc;

  if (w < 4) {
    // ---- PV waves: wave v -> (ri = v>>1, cf pair = (v&1)*2, +1), full K=1024 ----
    const int ri = w >> 1, cfp = (w & 1) * 2;
    f32x4 acc0 = {0.f, 0.f, 0.f, 0.f};
    f32x4 acc1 = {0.f, 0.f, 0.f, 0.f};
    __builtin_amdgcn_s_setprio(1);
#pragma unroll
    for (int ks = 0; ks < 32; ks++) {
      int kk = ks * 32;
      bf16x8 pa  = *(const bf16x8*)&E[eidx(ri * 16 + lr, kk + lg * 8)];
      bf16x8 vb0 = *(const bf16x8*)&Vg[(cfp * 16 + lr) * 1024 + kk + lg * 8];
      bf16x8 vb1 = *(const bf16x8*)&Vg[((cfp + 1) * 16 + lr) * 1024 + kk + lg * 8];
      acc0 = __builtin_amdgcn_mfma_f32_16x16x32_bf16(pa, vb0, acc0, 0, 0, 0);
      acc1 = __builtin_amdgcn_mfma_f32_16x16x32_bf16(pa, vb1, acc1, 0, 0, 0);
    }
    __builtin_amdgcn_s_setprio(0);
#pragma unroll
    for (int r = 0; r < 4; r++) {
      int row = ri * 16 + lg * 4 + r;
      float sf = __shfl(sfin_r, row);
      long base = (long)(b * 1024 + q0 + row) * 768 + h * 64;
      ctx[base + cfp * 16 + lr]       = f2bf(acc0[r] * sf);
      ctx[base + (cfp + 1) * 16 + lr] = f2bf(acc1[r] * sf);
    }
  } else {
    // ---- store waves: 4 waves (256 threads) stream 32 rows x 1024 f32 ----
    const int t = tid - 256;                 // 0..255
    float* wbase = wout + (long)(b * 1024 + q0) * 12288 + h * 1024;
#pragma unroll
    for (int row = 0; row < 32; row++) {
      float sf = __shfl(sfin_r, row);        // broadcast from lane 'row'
      int c4 = t * 4;
      u16x4 ev = *(const u16x4*)&E[eidx(row, c4)];
      f32x4 o;
      for (int j = 0; j < 4; j++) o[j] = bf2f(ev[j]) * sf;
      *(f32x4*)&wbase[(long)row * 12288 + c4] = o;
    }
  }
}

// ---------- kernel 4: dense GEMM y = ctx * wdb^T + bd (64x128 tile, 2-phase) ----------
__global__ __launch_bounds__(256) void dense_gemm(
    const unsigned short* __restrict__ ctx, const unsigned short* __restrict__ wdb,
    const float* __restrict__ bd, float* __restrict__ y)
{
  __shared__ unsigned short As[2][2048];
  __shared__ unsigned short Bs[2][4096];
  const int tid = threadIdx.x;
  const int bid = blockIdx.x;
  const int swz = (bid & 7) * 48 + (bid >> 3);
  const int bn = (swz % 6) * 128, bm = (swz / 6) * 64;
  const int w = tid >> 6, l = tid & 63;
  const int wr = w >> 1, wc = w & 1;
  const int lr = l & 15, lg = l >> 4;
  const int lofs = w << 9;

  f32x4 acc[2][4];
  for (int i = 0; i < 2; i++) for (int j = 0; j < 4; j++) acc[i][j] = {0.f, 0.f, 0.f, 0.f};

  const unsigned short* ga = ctx + (long)(bm + (tid >> 2)) * 768 + (tid & 3) * 8;
  const unsigned short* gb = wdb + (long)(bn + (tid >> 2)) * 768 + (tid & 3) * 8;

  gload16(ga,            &As[0][lofs]);
  gload16(gb,            &Bs[0][lofs]);
  gload16(gb + 64 * 768, &Bs[0][lofs + 2048]);
  __syncthreads();

  int cur = 0;
  for (int t = 0; t < 24; t++) {
    if (t < 23) {
      int k0 = (t + 1) * 32;
      gload16(ga + k0,            &As[cur ^ 1][lofs]);
      gload16(gb + k0,            &Bs[cur ^ 1][lofs]);
      gload16(gb + k0 + 64 * 768, &Bs[cur ^ 1][lofs + 2048]);
    }
    bf16x8 af[2], bfv[4];
    for (int i = 0; i < 2; i++) af[i]  = *(const bf16x8*)&As[cur][(wr * 32 + i * 16 + lr) * 32 + lg * 8];
    for (int j = 0; j < 4; j++) bfv[j] = *(const bf16x8*)&Bs[cur][(wc * 64 + j * 16 + lr) * 32 + lg * 8];
    for (int i = 0; i < 2; i++)
      for (int j = 0; j < 4; j++)
        acc[i][j] = __builtin_amdgcn_mfma_f32_16x16x32_bf16(af[i], bfv[j], acc[i][j], 0, 0, 0);
    __syncthreads();
    cur ^= 1;
  }

  for (int i = 0; i < 2; i++) for (int j = 0; j < 4; j++) {
    int col = bn + wc * 64 + j * 16 + lr;
    float bb = bd[col];
    for (int r = 0; r < 4; r++) {
      int row = bm + wr * 32 + i * 16 + lg * 4 + r;
      y[(long)row * 768 + col] = acc[i][j][r] + bb;
    }
  }
}

// ---------- kernel 5: LayerNorm ----------
__global__ __launch_bounds__(256) void ln_kernel(
    const float* __restrict__ y,
    const float* __restrict__ gamma, const float* __restrict__ beta,
    float* __restrict__ out)
{
  int w = threadIdx.x >> 6, l = threadIdx.x & 63;
  long row = blockIdx.x * 4 + w;
  const float* yr = y + row * 768;
  f32x4 v[3];
  float s = 0.f, ss = 0.f;
  for (int j = 0; j < 3; j++) {
    int c = j * 256 + l * 4;
    f32x4 t = *(const f32x4*)&yr[c];
    for (int q = 0; q < 4; q++) { s += t[q]; ss += t[q] * t[q]; }
    v[j] = t;
  }
  for (int o = 32; o >= 1; o >>= 1) { s += __shfl_xor(s, o); ss += __shfl_xor(ss, o); }
  float mu = s * (1.f / 768.f);
  float var = ss * (1.f / 768.f) - mu * mu;
  float rs = rsqrtf(var + 1e-12f);
  float* orow = out + row * 768;
  for (int j = 0; j < 3; j++) {
    int c = j * 256 + l * 4;
    f32x4 g = *(const f32x4*)&gamma[c];
    f32x4 be = *(const f32x4*)&beta[c];
    f32x4 o;
    for (int q = 0; q < 4; q++) o[q] = (v[j][q] - mu) * rs * g[q] + be[q];
    nt_store4(&orow[c], o);
  }
}

// ---------- launch ----------
extern "C" void kernel_launch(void* const* d_in, const int* in_sizes, int n_in,
                              void* d_out, int out_size, void* d_ws, size_t ws_size,
                              hipStream_t stream) {
  const float* x     = (const float*)d_in[0];
  const float* Wq    = (const float*)d_in[1];
  const float* bq    = (const float*)d_in[2];
  const float* Wk    = (const float*)d_in[3];
  const float* bk    = (const float*)d_in[4];
  const float* Wv    = (const float*)d_in[5];
  const float* bv    = (const float*)d_in[6];
  const float* Wd    = (const float*)d_in[7];
  const float* bd    = (const float*)d_in[8];
  const float* gamma = (const float*)d_in[9];
  const float* beta  = (const float*)d_in[10];
  float* out = (float*)d_out;

  char* ws = (char*)d_ws;
  unsigned short* xb  = (unsigned short*)(ws);
  unsigned short* wb  = (unsigned short*)(ws + 6291456);
  unsigned short* wdb = (unsigned short*)(ws + 9830400);
  unsigned short* Qb  = (unsigned short*)(ws + 11010048);
  unsigned short* Kb  = (unsigned short*)(ws + 17301504);
  unsigned short* Vt  = (unsigned short*)(ws + 23592960);
  unsigned short* ctx = (unsigned short*)(ws + 29884416);
  float*          yws = (float*)(ws + 11010048);

  prep<<<3840, 256, 0, stream>>>(x, Wq, Wk, Wv, Wd, xb, wb, wdb);
  qkv_gemm<<<576, 256, 0, stream>>>(xb, wb, bq, bk, bv, Qb, Kb, Vt);
  attn_kernel<<<1536, 512, 66560, stream>>>(Qb, Kb, Vt, out, ctx);
  dense_gemm<<<384, 256, 0, stream>>>(ctx, wdb, bd, yws);
  ln_kernel<<<1024, 256, 0, stream>>>(yws, gamma, beta, out + WOFF);
}